// Round 1
// baseline (950.213 us; speedup 1.0000x reference)
//
#include <hip/hip_runtime.h>
#include <stdint.h>

// SOM BMU search: B=8192 inputs [B,256], codebook [16384,256].
// argmin_n ||x-w_n|| == argmin_n (w2[n] - 2 x.w_n)  (x2 is per-row constant).
// Outputs: bmu_locations [8192,2] f32, losses [8192] f32, concatenated.

#define B_DIM 8192
#define V_DIM 256
#define N_DIM 16384

// ws layout: [0,64KB) w2 floats; [64KB,128KB) packed u64 per row.
#define WS_W2_BYTES 65536

// Monotone float->uint32 map so smaller float => smaller uint. Packed with idx
// in low 32 bits: atomicMin picks min value, then smallest index on ties
// (matches jnp.argmin first-occurrence semantics).
__device__ __forceinline__ unsigned long long packKey(float s, unsigned idx) {
    unsigned u = __float_as_uint(s);
    u = (u & 0x80000000u) ? ~u : (u | 0x80000000u);
    return ((unsigned long long)u << 32) | (unsigned long long)idx;
}

__global__ __launch_bounds__(256) void w2_kernel(const float* __restrict__ W,
                                                 float* __restrict__ w2) {
    int lane = threadIdx.x & 63;
    int wv   = threadIdx.x >> 6;
    int n    = blockIdx.x * 4 + wv;
    float4 v = ((const float4*)(W + (size_t)n * V_DIM))[lane];
    float s = v.x * v.x + v.y * v.y + v.z * v.z + v.w * v.w;
    #pragma unroll
    for (int m = 32; m >= 1; m >>= 1) s += __shfl_xor(s, m);
    if (lane == 0) w2[n] = s;
}

// Main kernel: 128x128 tile, K-step 32, 256 threads, 8x8 micro-tile.
// LDS is [k][row]-transposed so fragment reads are float4 (ds_read_b128).
#define BM 128
#define BN 128
#define KS 32
#define NSPLIT 16
#define CHUNK (N_DIM / NSPLIT) // 1024
#define NCT (CHUNK / BN)       // 8
#define LDSS 136               // k-row stride (floats): 544B, 16B aligned, pads banks

__global__ __launch_bounds__(256) void som_main(const float* __restrict__ X,
                                                const float* __restrict__ Wt,
                                                const float* __restrict__ w2,
                                                unsigned long long* __restrict__ packed) {
    __shared__ float Xs[KS][LDSS];
    __shared__ float Ws[KS][LDSS];

    const int t  = threadIdx.x;
    const int tx = t & 15;  // col group: cols 8*tx..8*tx+7 of tile
    const int ty = t >> 4;  // row group: rows 8*ty..8*ty+7 of tile
    const int rb = blockIdx.x >> 4;  // 64 row blocks
    const int nc = blockIdx.x & 15;  // 16 N chunks
    const int r0 = rb * BM;

    // staging role: thread covers row sr, k-half kq (16 floats = 4 float4)
    const int sr = t >> 1;
    const int kq = t & 1;

    float    minv[8];
    unsigned mini[8];
    #pragma unroll
    for (int i = 0; i < 8; ++i) { minv[i] = 3.4e38f; mini[i] = 0u; }

    for (int ct = 0; ct < NCT; ++ct) {
        const int c0 = nc * CHUNK + ct * BN;

        float acc[8][8];
        #pragma unroll
        for (int i = 0; i < 8; ++i)
            #pragma unroll
            for (int j = 0; j < 8; ++j) acc[i][j] = 0.0f;

        // prefetch k-step 0
        float4 xv[4], wv[4];
        {
            const float4* xg = (const float4*)(X  + (size_t)(r0 + sr) * V_DIM) + kq * 4;
            const float4* wg = (const float4*)(Wt + (size_t)(c0 + sr) * V_DIM) + kq * 4;
            #pragma unroll
            for (int q = 0; q < 4; ++q) { xv[q] = xg[q]; wv[q] = wg[q]; }
        }

        for (int ks = 0; ks < V_DIM / KS; ++ks) {
            __syncthreads(); // previous compute done; LDS reusable
            // transposed scatter: Xs[k][row], Ws[k][col]
            #pragma unroll
            for (int q = 0; q < 4; ++q) {
                const int kb = kq * 16 + q * 4;
                Xs[kb + 0][sr] = xv[q].x; Xs[kb + 1][sr] = xv[q].y;
                Xs[kb + 2][sr] = xv[q].z; Xs[kb + 3][sr] = xv[q].w;
                Ws[kb + 0][sr] = wv[q].x; Ws[kb + 1][sr] = wv[q].y;
                Ws[kb + 2][sr] = wv[q].z; Ws[kb + 3][sr] = wv[q].w;
            }
            __syncthreads();

            if (ks < V_DIM / KS - 1) { // prefetch next k-step, hides under compute
                const int k0n = (ks + 1) * KS;
                const float4* xg = (const float4*)(X  + (size_t)(r0 + sr) * V_DIM + k0n) + kq * 4;
                const float4* wg = (const float4*)(Wt + (size_t)(c0 + sr) * V_DIM + k0n) + kq * 4;
                #pragma unroll
                for (int q = 0; q < 4; ++q) { xv[q] = xg[q]; wv[q] = wg[q]; }
            }

            const float* ap = &Xs[0][ty * 8];
            const float* bp = &Ws[0][tx * 8];
            #pragma unroll 8
            for (int kk = 0; kk < KS; ++kk) {
                float4 a0 = *(const float4*)(ap + kk * LDSS);
                float4 a1 = *(const float4*)(ap + kk * LDSS + 4);
                float4 b0 = *(const float4*)(bp + kk * LDSS);
                float4 b1 = *(const float4*)(bp + kk * LDSS + 4);
                float a[8] = {a0.x, a0.y, a0.z, a0.w, a1.x, a1.y, a1.z, a1.w};
                float b[8] = {b0.x, b0.y, b0.z, b0.w, b1.x, b1.y, b1.z, b1.w};
                #pragma unroll
                for (int i = 0; i < 8; ++i)
                    #pragma unroll
                    for (int j = 0; j < 8; ++j)
                        acc[i][j] = fmaf(a[i], b[j], acc[i][j]);
            }
        }

        // score + running min (n ascending within thread => strict < keeps first)
        #pragma unroll
        for (int j = 0; j < 8; ++j) {
            const unsigned n = (unsigned)(c0 + tx * 8 + j);
            const float w2v = w2[n];
            #pragma unroll
            for (int i = 0; i < 8; ++i) {
                const float s = fmaf(-2.0f, acc[i][j], w2v);
                if (s < minv[i]) { minv[i] = s; mini[i] = n; }
            }
        }
    }

    // reduce across the 16 tx lanes sharing each row (consecutive lanes in-wave)
    #pragma unroll
    for (int i = 0; i < 8; ++i) {
        float v = minv[i];
        unsigned idx = mini[i];
        #pragma unroll
        for (int m = 1; m <= 8; m <<= 1) {
            float    ov = __shfl_xor(v, m);
            unsigned oi = (unsigned)__shfl_xor((int)idx, m);
            if (ov < v || (ov == v && oi < idx)) { v = ov; idx = oi; }
        }
        if (tx == 0) atomicMin(&packed[r0 + ty * 8 + i], packKey(v, idx));
    }
}

__global__ __launch_bounds__(256) void finalize(const float* __restrict__ X,
                                                const float* __restrict__ loc,
                                                const unsigned long long* __restrict__ packed,
                                                float* __restrict__ out) {
    int lane = threadIdx.x & 63;
    int wv   = threadIdx.x >> 6;
    int b    = blockIdx.x * 4 + wv;
    float4 v = ((const float4*)(X + (size_t)b * V_DIM))[lane];
    float x2 = v.x * v.x + v.y * v.y + v.z * v.z + v.w * v.w;
    #pragma unroll
    for (int m = 32; m >= 1; m >>= 1) x2 += __shfl_xor(x2, m);
    if (lane == 0) {
        unsigned long long p = packed[b];
        unsigned key = (unsigned)(p >> 32);
        unsigned idx = (unsigned)(p & 0xFFFFFFFFu);
        unsigned sb  = (key & 0x80000000u) ? (key & 0x7FFFFFFFu) : ~key;
        float s  = __uint_as_float(sb);
        float d2 = fmaxf(x2 + s, 0.0f);
        out[2 * b]     = loc[2 * idx];
        out[2 * b + 1] = loc[2 * idx + 1];
        out[2 * B_DIM + b] = sqrtf(d2);
    }
}

extern "C" void kernel_launch(void* const* d_in, const int* in_sizes, int n_in,
                              void* d_out, int out_size, void* d_ws, size_t ws_size,
                              hipStream_t stream) {
    const float* X = (const float*)d_in[0];   // [8192,256]
    const float* W = (const float*)d_in[1];   // [16384,256]
    const float* L = (const float*)d_in[2];   // [16384,2]
    float* out = (float*)d_out;               // [8192*2 | 8192]

    float* w2 = (float*)d_ws;
    unsigned long long* packed = (unsigned long long*)((char*)d_ws + WS_W2_BYTES);

    hipMemsetAsync(packed, 0xFF, B_DIM * sizeof(unsigned long long), stream);
    w2_kernel<<<N_DIM / 4, 256, 0, stream>>>(W, w2);
    som_main<<<(B_DIM / BM) * NSPLIT, 256, 0, stream>>>(X, W, w2, packed);
    finalize<<<B_DIM / 4, 256, 0, stream>>>(X, L, packed, out);
}

// Round 2
// 312.647 us; speedup vs baseline: 3.0393x; 3.0393x over previous
//
#include <hip/hip_runtime.h>
#include <stdint.h>

// SOM BMU search: B=8192 inputs [B,256], codebook [16384,256].
// argmin_n ||x-w_n|| == argmin_n (w2[n] - 2 x.w_n)  (x2 per-row constant).
// Engine: bf16 hi/lo split GEMM on MFMA. x.w ~= xh.wh + xh.wl + xl.wh
// (lo*lo dropped, ~2^-18 relative -- below fp32 GEMM rounding).

#define B_DIM 8192
#define V_DIM 256
#define N_DIM 16384
#define WS_W2_BYTES 65536

typedef __attribute__((ext_vector_type(8))) short short8;
typedef __attribute__((ext_vector_type(4))) float f32x4;

__device__ __forceinline__ unsigned long long packKey(float s, unsigned idx) {
    unsigned u = __float_as_uint(s);
    u = (u & 0x80000000u) ? ~u : (u | 0x80000000u);
    return ((unsigned long long)u << 32) | (unsigned long long)idx;
}

__global__ __launch_bounds__(256) void w2_kernel(const float* __restrict__ W,
                                                 float* __restrict__ w2) {
    int lane = threadIdx.x & 63;
    int wv   = threadIdx.x >> 6;
    int n    = blockIdx.x * 4 + wv;
    float4 v = ((const float4*)(W + (size_t)n * V_DIM))[lane];
    float s = v.x * v.x + v.y * v.y + v.z * v.z + v.w * v.w;
    #pragma unroll
    for (int m = 32; m >= 1; m >>= 1) s += __shfl_xor(s, m);
    if (lane == 0) w2[n] = s;
}

// ---- bf16 hi/lo packing (truncation for hi; lo compensates, err ~2^-17) ----
__device__ __forceinline__ unsigned packhi2(float a, float b) {
    return (__float_as_uint(a) >> 16) | (__float_as_uint(b) & 0xFFFF0000u);
}
__device__ __forceinline__ unsigned packlo2(float a, float b) {
    float ah = __uint_as_float(__float_as_uint(a) & 0xFFFF0000u);
    float bh = __uint_as_float(__float_as_uint(b) & 0xFFFF0000u);
    return (__float_as_uint(a - ah) >> 16) | (__float_as_uint(b - bh) & 0xFFFF0000u);
}
__device__ __forceinline__ uint4 mku4(unsigned a, unsigned b, unsigned c, unsigned d) {
    uint4 r; r.x = a; r.y = b; r.z = c; r.w = d; return r;
}
__device__ __forceinline__ uint4 hi8(float4 p, float4 q) {
    return mku4(packhi2(p.x, p.y), packhi2(p.z, p.w), packhi2(q.x, q.y), packhi2(q.z, q.w));
}
__device__ __forceinline__ uint4 lo8(float4 p, float4 q) {
    return mku4(packlo2(p.x, p.y), packlo2(p.z, p.w), packlo2(q.x, q.y), packlo2(q.z, q.w));
}

// LDS plane layout: [row][k] bf16, row stride 64B (BK=32), 16B slots XOR-swizzled
// so both b128 writes and frag b128 reads hit all 8 bank-groups evenly.
__device__ __forceinline__ int lb(int row, int slot) {
    return row * 64 + ((slot ^ ((row >> 1) & 3)) << 4);
}

#define BM 128
#define BN 128
#define BK 32
#define KSTEPS (V_DIM / BK) // 8

__global__ __launch_bounds__(256, 2) void som_mfma(const float* __restrict__ X,
                                                   const float* __restrict__ W,
                                                   const float* __restrict__ w2,
                                                   unsigned long long* __restrict__ packed) {
    __shared__ char lds[4 * 8192]; // Ahi | Alo | Bhi | Blo, 8KB each
    char* Ahi = lds;
    char* Alo = lds + 8192;
    char* Bhi = lds + 16384;
    char* Blo = lds + 24576;

    const int t     = threadIdx.x;
    const int lane  = t & 63;
    const int wv    = t >> 6;
    const int wr    = wv >> 1, wc = wv & 1; // wave quadrant (64x64)
    const int fr    = lane & 15;            // frag row/col
    const int kslot = lane >> 4;            // 8-k slot

    const int rb = blockIdx.x >> 7;  // 64 row-blocks (cb fastest: A-reuse in L2)
    const int cb = blockIdx.x & 127; // 128 col-blocks
    const int r0 = rb * BM, c0 = cb * BN;

    // staging role: row sr, k-half sh (16 floats = 4 float4)
    const int sr = t >> 1;
    const int sh = t & 1;
    const float* xg = X + (size_t)(r0 + sr) * V_DIM + sh * 16;
    const float* wg = W + (size_t)(c0 + sr) * V_DIM + sh * 16;

    float4 pa[4], pb[4];
    #pragma unroll
    for (int q = 0; q < 4; ++q) {
        pa[q] = ((const float4*)xg)[q];
        pb[q] = ((const float4*)wg)[q];
    }

    f32x4 acc[4][4];
    #pragma unroll
    for (int i = 0; i < 4; ++i)
        #pragma unroll
        for (int j = 0; j < 4; ++j)
            acc[i][j] = (f32x4){0.f, 0.f, 0.f, 0.f};

    for (int ks = 0; ks < KSTEPS; ++ks) {
        // convert in regs (outside the barrier window)
        uint4 cah0 = hi8(pa[0], pa[1]), cah1 = hi8(pa[2], pa[3]);
        uint4 cal0 = lo8(pa[0], pa[1]), cal1 = lo8(pa[2], pa[3]);
        uint4 cbh0 = hi8(pb[0], pb[1]), cbh1 = hi8(pb[2], pb[3]);
        uint4 cbl0 = lo8(pb[0], pb[1]), cbl1 = lo8(pb[2], pb[3]);

        __syncthreads(); // previous compute done; LDS reusable
        *(uint4*)(Ahi + lb(sr, 2 * sh))     = cah0;
        *(uint4*)(Ahi + lb(sr, 2 * sh + 1)) = cah1;
        *(uint4*)(Alo + lb(sr, 2 * sh))     = cal0;
        *(uint4*)(Alo + lb(sr, 2 * sh + 1)) = cal1;
        *(uint4*)(Bhi + lb(sr, 2 * sh))     = cbh0;
        *(uint4*)(Bhi + lb(sr, 2 * sh + 1)) = cbh1;
        *(uint4*)(Blo + lb(sr, 2 * sh))     = cbl0;
        *(uint4*)(Blo + lb(sr, 2 * sh + 1)) = cbl1;
        __syncthreads();

        if (ks + 1 < KSTEPS) { // prefetch next K-step (overlaps MFMA below)
            const float* xn = xg + (ks + 1) * BK;
            const float* wn = wg + (ks + 1) * BK;
            #pragma unroll
            for (int q = 0; q < 4; ++q) {
                pa[q] = ((const float4*)xn)[q];
                pb[q] = ((const float4*)wn)[q];
            }
        }

        short8 fah[4], fal[4], fbh[4], fbl[4];
        #pragma unroll
        for (int i = 0; i < 4; ++i) {
            int row = wr * 64 + i * 16 + fr;
            fah[i] = *(const short8*)(Ahi + lb(row, kslot));
            fal[i] = *(const short8*)(Alo + lb(row, kslot));
        }
        #pragma unroll
        for (int j = 0; j < 4; ++j) {
            int col = wc * 64 + j * 16 + fr;
            fbh[j] = *(const short8*)(Bhi + lb(col, kslot));
            fbl[j] = *(const short8*)(Blo + lb(col, kslot));
        }
        #pragma unroll
        for (int i = 0; i < 4; ++i)
            #pragma unroll
            for (int j = 0; j < 4; ++j) {
                acc[i][j] = __builtin_amdgcn_mfma_f32_16x16x32_bf16(fah[i], fbh[j], acc[i][j], 0, 0, 0);
                acc[i][j] = __builtin_amdgcn_mfma_f32_16x16x32_bf16(fah[i], fbl[j], acc[i][j], 0, 0, 0);
                acc[i][j] = __builtin_amdgcn_mfma_f32_16x16x32_bf16(fal[i], fbh[j], acc[i][j], 0, 0, 0);
            }
    }

    // epilogue: s = w2[n] - 2*dot; per-row min+argmin; global merge via atomicMin
    float w2v[4];
    #pragma unroll
    for (int j = 0; j < 4; ++j) w2v[j] = w2[c0 + wc * 64 + j * 16 + fr];

    #pragma unroll
    for (int i = 0; i < 4; ++i) {
        #pragma unroll
        for (int r = 0; r < 4; ++r) {
            const int row = r0 + wr * 64 + i * 16 + kslot * 4 + r; // C: row=(l>>4)*4+reg
            float best = 3.4e38f;
            unsigned bidx = 0u;
            #pragma unroll
            for (int j = 0; j < 4; ++j) {
                const unsigned n = (unsigned)(c0 + wc * 64 + j * 16 + fr); // C: col=l&15
                const float s = fmaf(-2.0f, acc[i][j][r], w2v[j]);
                if (s < best) { best = s; bidx = n; } // j ascending => first-min kept
            }
            #pragma unroll
            for (int m = 1; m <= 8; m <<= 1) { // reduce across the 16 fr-lanes
                float    ov = __shfl_xor(best, m);
                unsigned oi = (unsigned)__shfl_xor((int)bidx, m);
                if (ov < best || (ov == best && oi < bidx)) { best = ov; bidx = oi; }
            }
            if (fr == 0) atomicMin(&packed[row], packKey(best, bidx));
        }
    }
}

__global__ __launch_bounds__(256) void finalize(const float* __restrict__ X,
                                                const float* __restrict__ loc,
                                                const unsigned long long* __restrict__ packed,
                                                float* __restrict__ out) {
    int lane = threadIdx.x & 63;
    int wv   = threadIdx.x >> 6;
    int b    = blockIdx.x * 4 + wv;
    float4 v = ((const float4*)(X + (size_t)b * V_DIM))[lane];
    float x2 = v.x * v.x + v.y * v.y + v.z * v.z + v.w * v.w;
    #pragma unroll
    for (int m = 32; m >= 1; m >>= 1) x2 += __shfl_xor(x2, m);
    if (lane == 0) {
        unsigned long long p = packed[b];
        unsigned key = (unsigned)(p >> 32);
        unsigned idx = (unsigned)(p & 0xFFFFFFFFu);
        unsigned sb  = (key & 0x80000000u) ? (key & 0x7FFFFFFFu) : ~key;
        float s  = __uint_as_float(sb);
        float d2 = fmaxf(x2 + s, 0.0f);
        out[2 * b]     = loc[2 * idx];
        out[2 * b + 1] = loc[2 * idx + 1];
        out[2 * B_DIM + b] = sqrtf(d2);
    }
}

extern "C" void kernel_launch(void* const* d_in, const int* in_sizes, int n_in,
                              void* d_out, int out_size, void* d_ws, size_t ws_size,
                              hipStream_t stream) {
    const float* X = (const float*)d_in[0];   // [8192,256]
    const float* W = (const float*)d_in[1];   // [16384,256]
    const float* L = (const float*)d_in[2];   // [16384,2]
    float* out = (float*)d_out;               // [8192*2 | 8192]

    float* w2 = (float*)d_ws;
    unsigned long long* packed = (unsigned long long*)((char*)d_ws + WS_W2_BYTES);

    hipMemsetAsync(packed, 0xFF, B_DIM * sizeof(unsigned long long), stream);
    w2_kernel<<<N_DIM / 4, 256, 0, stream>>>(W, w2);
    som_mfma<<<(B_DIM / BM) * (N_DIM / BN), 256, 0, stream>>>(X, W, w2, packed);
    finalize<<<B_DIM / 4, 256, 0, stream>>>(X, L, packed, out);
}

// Round 3
// 286.821 us; speedup vs baseline: 3.3129x; 1.0900x over previous
//
#include <hip/hip_runtime.h>
#include <stdint.h>

// SOM BMU search: B=8192 inputs [B,256], codebook [16384,256].
// argmin_n ||x-w_n|| == argmin_n (w2[n] - 2 x.w_n)  (x2 per-row constant).
// Engine: bf16 hi/lo split GEMM on MFMA. x.w ~= xh.wh + xh.wl + xl.wh.
// Fast path: hi/lo planes precomputed into d_ws, pre-swizzled to the LDS
// image layout, staged via width-16 global_load_lds. Fallback (small ws):
// round-2 reg-staged kernel.

#define B_DIM 8192
#define V_DIM 256
#define N_DIM 16384

#define WS_W2_OFF     0
#define WS_PACKED_OFF 65536
#define WS_PLANES_OFF 131072
#define XPLANE_BYTES  (B_DIM * V_DIM * 2)   // 4MB
#define WPLANE_BYTES  (N_DIM * V_DIM * 2)   // 8MB
#define WS_FAST_NEED  (WS_PLANES_OFF + 2 * XPLANE_BYTES + 2 * WPLANE_BYTES)

typedef __attribute__((ext_vector_type(8))) short short8;
typedef __attribute__((ext_vector_type(4))) float f32x4;

__device__ __forceinline__ unsigned long long packKey(float s, unsigned idx) {
    unsigned u = __float_as_uint(s);
    u = (u & 0x80000000u) ? ~u : (u | 0x80000000u);
    return ((unsigned long long)u << 32) | (unsigned long long)idx;
}

__global__ __launch_bounds__(256) void w2_kernel(const float* __restrict__ W,
                                                 float* __restrict__ w2) {
    int lane = threadIdx.x & 63;
    int wv   = threadIdx.x >> 6;
    int n    = blockIdx.x * 4 + wv;
    float4 v = ((const float4*)(W + (size_t)n * V_DIM))[lane];
    float s = v.x * v.x + v.y * v.y + v.z * v.z + v.w * v.w;
    #pragma unroll
    for (int m = 32; m >= 1; m >>= 1) s += __shfl_xor(s, m);
    if (lane == 0) w2[n] = s;
}

// ---------------- fast path ----------------

// RNE f32->bf16
__device__ __forceinline__ unsigned bfrn(float x) {
    unsigned u = __float_as_uint(x);
    return (u + 0x7FFFu + ((u >> 16) & 1u)) >> 16;
}
__device__ __forceinline__ float bf2f(unsigned h) { return __uint_as_float(h << 16); }

// Convert X,W into hi/lo bf16 planes, pre-swizzled: within each 32-k window
// (4 slots of 16B), slot s stored at s ^ ((row>>1)&3). This is the exact LDS
// image som_fast's linear global_load_lds expects; ds_read applies the same XOR.
__global__ __launch_bounds__(256) void convert_planes(const float* __restrict__ X,
                                                      const float* __restrict__ W,
                                                      unsigned short* __restrict__ Xh,
                                                      unsigned short* __restrict__ Xl,
                                                      unsigned short* __restrict__ Wh,
                                                      unsigned short* __restrict__ Wl) {
    int gid = blockIdx.x * 256 + threadIdx.x;
    int s   = gid & 31;        // 16B slot within 512B row (8 floats)
    int row = gid >> 5;
    const float* src;
    unsigned short *dh, *dl;
    int r;
    if (row < B_DIM) { r = row; src = X + (size_t)r * V_DIM; dh = Xh; dl = Xl; }
    else             { r = row - B_DIM; src = W + (size_t)r * V_DIM; dh = Wh; dl = Wl; }

    float4 a = ((const float4*)src)[s * 2];
    float4 b = ((const float4*)src)[s * 2 + 1];
    float v[8] = {a.x, a.y, a.z, a.w, b.x, b.y, b.z, b.w};
    unsigned hi[8], lo[8];
    #pragma unroll
    for (int i = 0; i < 8; ++i) {
        hi[i] = bfrn(v[i]);
        lo[i] = bfrn(v[i] - bf2f(hi[i]));
    }
    uint4 hp, lp;
    hp.x = hi[0] | (hi[1] << 16); hp.y = hi[2] | (hi[3] << 16);
    hp.z = hi[4] | (hi[5] << 16); hp.w = hi[6] | (hi[7] << 16);
    lp.x = lo[0] | (lo[1] << 16); lp.y = lo[2] | (lo[3] << 16);
    lp.z = lo[4] | (lo[5] << 16); lp.w = lo[6] | (lo[7] << 16);

    int sp = (s & ~3) | ((s & 3) ^ ((r >> 1) & 3)); // pre-swizzle
    *(uint4*)(dh + (size_t)r * V_DIM + sp * 8) = hp;
    *(uint4*)(dl + (size_t)r * V_DIM + sp * 8) = lp;
}

__device__ __forceinline__ void gl16(const void* g, void* l) {
    __builtin_amdgcn_global_load_lds((const __attribute__((address_space(1))) unsigned int*)g,
                                     (__attribute__((address_space(3))) unsigned int*)l,
                                     16, 0, 0);
}

#define BM 128
#define BN 128
#define FBK 32
#define FKSTEPS (V_DIM / FBK) // 8

__global__ __launch_bounds__(256) void som_fast(const unsigned short* __restrict__ Xh,
                                                const unsigned short* __restrict__ Xl,
                                                const unsigned short* __restrict__ Wh,
                                                const unsigned short* __restrict__ Wl,
                                                const float* __restrict__ w2,
                                                unsigned long long* __restrict__ packed) {
    __shared__ char lds[32768]; // Ah | Al | Bh | Bl, 8KB each ([128 rows][64B])
    char* Ah = lds;
    char* Al = lds + 8192;
    char* Bh = lds + 16384;
    char* Bl = lds + 24576;

    const int t    = threadIdx.x;
    const int lane = t & 63;
    const int wv   = t >> 6;
    const int wr   = wv >> 1, wc = wv & 1; // wave quadrant (64x64)
    const int fr   = lane & 15;            // frag row/col
    const int kq   = lane >> 4;            // 16B k-slot within 32-k slice

    const int rb = blockIdx.x >> 7;
    const int cb = blockIdx.x & 127;
    const int r0 = rb * BM, c0 = cb * BN;

    // staging: thread covers (row = t>>2, slot = t&3) of each 8KB plane tile,
    // for q in {0,1} rows +0 / +64. ws is pre-swizzled => pure linear copy.
    const size_t aOff = (size_t)(r0 + (t >> 2)) * V_DIM + (t & 3) * 8;
    const size_t bOff = (size_t)(c0 + (t >> 2)) * V_DIM + (t & 3) * 8;
    const unsigned short* sXh = Xh + aOff;
    const unsigned short* sXl = Xl + aOff;
    const unsigned short* sWh = Wh + bOff;
    const unsigned short* sWl = Wl + bOff;
    const int t16 = t * 16;

#define ISSUE(ks)                                                          \
    do {                                                                   \
        gl16(sXh + (ks) * FBK,            Ah + t16);                       \
        gl16(sXh + 64 * V_DIM + (ks) * FBK, Ah + 4096 + t16);              \
        gl16(sXl + (ks) * FBK,            Al + t16);                       \
        gl16(sXl + 64 * V_DIM + (ks) * FBK, Al + 4096 + t16);              \
        gl16(sWh + (ks) * FBK,            Bh + t16);                       \
        gl16(sWh + 64 * V_DIM + (ks) * FBK, Bh + 4096 + t16);              \
        gl16(sWl + (ks) * FBK,            Bl + t16);                       \
        gl16(sWl + 64 * V_DIM + (ks) * FBK, Bl + 4096 + t16);              \
    } while (0)

    f32x4 acc[4][4];
    #pragma unroll
    for (int i = 0; i < 4; ++i)
        #pragma unroll
        for (int j = 0; j < 4; ++j)
            acc[i][j] = (f32x4){0.f, 0.f, 0.f, 0.f};

    ISSUE(0);

    for (int ks = 0; ks < FKSTEPS; ++ks) {
        __syncthreads(); // drains vmcnt(0): step ks resident; LDS write-safe

        short8 fah[4], fal[4], fbh[4], fbl[4];
        #pragma unroll
        for (int i = 0; i < 4; ++i) {
            const int row = wr * 64 + i * 16 + fr;
            const int off = row * 64 + ((kq ^ ((row >> 1) & 3)) << 4);
            fah[i] = *(const short8*)(Ah + off);
            fal[i] = *(const short8*)(Al + off);
        }
        #pragma unroll
        for (int j = 0; j < 4; ++j) {
            const int col = wc * 64 + j * 16 + fr;
            const int off = col * 64 + ((kq ^ ((col >> 1) & 3)) << 4);
            fbh[j] = *(const short8*)(Bh + off);
            fbl[j] = *(const short8*)(Bl + off);
        }
        __syncthreads(); // all reads done; LDS reusable

        if (ks + 1 < FKSTEPS) ISSUE(ks + 1); // flies under the MFMAs below

        #pragma unroll
        for (int i = 0; i < 4; ++i)
            #pragma unroll
            for (int j = 0; j < 4; ++j) {
                acc[i][j] = __builtin_amdgcn_mfma_f32_16x16x32_bf16(fah[i], fbh[j], acc[i][j], 0, 0, 0);
                acc[i][j] = __builtin_amdgcn_mfma_f32_16x16x32_bf16(fah[i], fbl[j], acc[i][j], 0, 0, 0);
                acc[i][j] = __builtin_amdgcn_mfma_f32_16x16x32_bf16(fal[i], fbh[j], acc[i][j], 0, 0, 0);
            }
    }
#undef ISSUE

    float w2v[4];
    #pragma unroll
    for (int j = 0; j < 4; ++j) w2v[j] = w2[c0 + wc * 64 + j * 16 + fr];

    #pragma unroll
    for (int i = 0; i < 4; ++i) {
        #pragma unroll
        for (int r = 0; r < 4; ++r) {
            const int row = r0 + wr * 64 + i * 16 + kq * 4 + r; // C: row=(l>>4)*4+reg
            float best = 3.4e38f;
            unsigned bidx = 0u;
            #pragma unroll
            for (int j = 0; j < 4; ++j) {
                const unsigned n = (unsigned)(c0 + wc * 64 + j * 16 + fr); // C: col=l&15
                const float s = fmaf(-2.0f, acc[i][j][r], w2v[j]);
                if (s < best) { best = s; bidx = n; }
            }
            #pragma unroll
            for (int m = 1; m <= 8; m <<= 1) {
                float    ov = __shfl_xor(best, m);
                unsigned oi = (unsigned)__shfl_xor((int)bidx, m);
                if (ov < best || (ov == best && oi < bidx)) { best = ov; bidx = oi; }
            }
            if (fr == 0) atomicMin(&packed[row], packKey(best, bidx));
        }
    }
}

// ---------------- fallback path (round-2 kernel, proven) ----------------

__device__ __forceinline__ unsigned packhi2(float a, float b) {
    return (__float_as_uint(a) >> 16) | (__float_as_uint(b) & 0xFFFF0000u);
}
__device__ __forceinline__ unsigned packlo2(float a, float b) {
    float ah = __uint_as_float(__float_as_uint(a) & 0xFFFF0000u);
    float bh = __uint_as_float(__float_as_uint(b) & 0xFFFF0000u);
    return (__float_as_uint(a - ah) >> 16) | (__float_as_uint(b - bh) & 0xFFFF0000u);
}
__device__ __forceinline__ uint4 mku4(unsigned a, unsigned b, unsigned c, unsigned d) {
    uint4 r; r.x = a; r.y = b; r.z = c; r.w = d; return r;
}
__device__ __forceinline__ uint4 hi8(float4 p, float4 q) {
    return mku4(packhi2(p.x, p.y), packhi2(p.z, p.w), packhi2(q.x, q.y), packhi2(q.z, q.w));
}
__device__ __forceinline__ uint4 lo8(float4 p, float4 q) {
    return mku4(packlo2(p.x, p.y), packlo2(p.z, p.w), packlo2(q.x, q.y), packlo2(q.z, q.w));
}
__device__ __forceinline__ int lb(int row, int slot) {
    return row * 64 + ((slot ^ ((row >> 1) & 3)) << 4);
}

__global__ __launch_bounds__(256, 2) void som_mfma(const float* __restrict__ X,
                                                   const float* __restrict__ W,
                                                   const float* __restrict__ w2,
                                                   unsigned long long* __restrict__ packed) {
    __shared__ char lds[4 * 8192];
    char* Ahp = lds;
    char* Alp = lds + 8192;
    char* Bhp = lds + 16384;
    char* Blp = lds + 24576;

    const int t     = threadIdx.x;
    const int lane  = t & 63;
    const int wv    = t >> 6;
    const int wr    = wv >> 1, wc = wv & 1;
    const int fr    = lane & 15;
    const int kslot = lane >> 4;

    const int rb = blockIdx.x >> 7;
    const int cb = blockIdx.x & 127;
    const int r0 = rb * BM, c0 = cb * BN;

    const int sr = t >> 1;
    const int sh = t & 1;
    const float* xg = (const float*)X + (size_t)(r0 + sr) * V_DIM + sh * 16;
    const float* wg = (const float*)W + (size_t)(c0 + sr) * V_DIM + sh * 16;

    float4 pa[4], pb[4];
    #pragma unroll
    for (int q = 0; q < 4; ++q) { pa[q] = ((const float4*)xg)[q]; pb[q] = ((const float4*)wg)[q]; }

    f32x4 acc[4][4];
    #pragma unroll
    for (int i = 0; i < 4; ++i)
        #pragma unroll
        for (int j = 0; j < 4; ++j) acc[i][j] = (f32x4){0.f, 0.f, 0.f, 0.f};

    for (int ks = 0; ks < 8; ++ks) {
        uint4 cah0 = hi8(pa[0], pa[1]), cah1 = hi8(pa[2], pa[3]);
        uint4 cal0 = lo8(pa[0], pa[1]), cal1 = lo8(pa[2], pa[3]);
        uint4 cbh0 = hi8(pb[0], pb[1]), cbh1 = hi8(pb[2], pb[3]);
        uint4 cbl0 = lo8(pb[0], pb[1]), cbl1 = lo8(pb[2], pb[3]);

        __syncthreads();
        *(uint4*)(Ahp + lb(sr, 2 * sh))     = cah0;
        *(uint4*)(Ahp + lb(sr, 2 * sh + 1)) = cah1;
        *(uint4*)(Alp + lb(sr, 2 * sh))     = cal0;
        *(uint4*)(Alp + lb(sr, 2 * sh + 1)) = cal1;
        *(uint4*)(Bhp + lb(sr, 2 * sh))     = cbh0;
        *(uint4*)(Bhp + lb(sr, 2 * sh + 1)) = cbh1;
        *(uint4*)(Blp + lb(sr, 2 * sh))     = cbl0;
        *(uint4*)(Blp + lb(sr, 2 * sh + 1)) = cbl1;
        __syncthreads();

        if (ks + 1 < 8) {
            const float* xn = xg + (ks + 1) * 32;
            const float* wn = wg + (ks + 1) * 32;
            #pragma unroll
            for (int q = 0; q < 4; ++q) { pa[q] = ((const float4*)xn)[q]; pb[q] = ((const float4*)wn)[q]; }
        }

        short8 fah[4], fal[4], fbh[4], fbl[4];
        #pragma unroll
        for (int i = 0; i < 4; ++i) {
            int row = wr * 64 + i * 16 + fr;
            fah[i] = *(const short8*)(Ahp + lb(row, kslot));
            fal[i] = *(const short8*)(Alp + lb(row, kslot));
        }
        #pragma unroll
        for (int j = 0; j < 4; ++j) {
            int col = wc * 64 + j * 16 + fr;
            fbh[j] = *(const short8*)(Bhp + lb(col, kslot));
            fbl[j] = *(const short8*)(Blp + lb(col, kslot));
        }
        #pragma unroll
        for (int i = 0; i < 4; ++i)
            #pragma unroll
            for (int j = 0; j < 4; ++j) {
                acc[i][j] = __builtin_amdgcn_mfma_f32_16x16x32_bf16(fah[i], fbh[j], acc[i][j], 0, 0, 0);
                acc[i][j] = __builtin_amdgcn_mfma_f32_16x16x32_bf16(fah[i], fbl[j], acc[i][j], 0, 0, 0);
                acc[i][j] = __builtin_amdgcn_mfma_f32_16x16x32_bf16(fal[i], fbh[j], acc[i][j], 0, 0, 0);
            }
    }

    float w2v[4];
    #pragma unroll
    for (int j = 0; j < 4; ++j) w2v[j] = w2[c0 + wc * 64 + j * 16 + fr];

    #pragma unroll
    for (int i = 0; i < 4; ++i) {
        #pragma unroll
        for (int r = 0; r < 4; ++r) {
            const int row = r0 + wr * 64 + i * 16 + kslot * 4 + r;
            float best = 3.4e38f;
            unsigned bidx = 0u;
            #pragma unroll
            for (int j = 0; j < 4; ++j) {
                const unsigned n = (unsigned)(c0 + wc * 64 + j * 16 + fr);
                const float s = fmaf(-2.0f, acc[i][j][r], w2v[j]);
                if (s < best) { best = s; bidx = n; }
            }
            #pragma unroll
            for (int m = 1; m <= 8; m <<= 1) {
                float    ov = __shfl_xor(best, m);
                unsigned oi = (unsigned)__shfl_xor((int)bidx, m);
                if (ov < best || (ov == best && oi < bidx)) { best = ov; bidx = oi; }
            }
            if (fr == 0) atomicMin(&packed[row], packKey(best, bidx));
        }
    }
}

__global__ __launch_bounds__(256) void finalize(const float* __restrict__ X,
                                                const float* __restrict__ loc,
                                                const unsigned long long* __restrict__ packed,
                                                float* __restrict__ out) {
    int lane = threadIdx.x & 63;
    int wv   = threadIdx.x >> 6;
    int b    = blockIdx.x * 4 + wv;
    float4 v = ((const float4*)(X + (size_t)b * V_DIM))[lane];
    float x2 = v.x * v.x + v.y * v.y + v.z * v.z + v.w * v.w;
    #pragma unroll
    for (int m = 32; m >= 1; m >>= 1) x2 += __shfl_xor(x2, m);
    if (lane == 0) {
        unsigned long long p = packed[b];
        unsigned key = (unsigned)(p >> 32);
        unsigned idx = (unsigned)(p & 0xFFFFFFFFu);
        unsigned sb  = (key & 0x80000000u) ? (key & 0x7FFFFFFFu) : ~key;
        float s  = __uint_as_float(sb);
        float d2 = fmaxf(x2 + s, 0.0f);
        out[2 * b]     = loc[2 * idx];
        out[2 * b + 1] = loc[2 * idx + 1];
        out[2 * B_DIM + b] = sqrtf(d2);
    }
}

extern "C" void kernel_launch(void* const* d_in, const int* in_sizes, int n_in,
                              void* d_out, int out_size, void* d_ws, size_t ws_size,
                              hipStream_t stream) {
    const float* X = (const float*)d_in[0];   // [8192,256]
    const float* W = (const float*)d_in[1];   // [16384,256]
    const float* L = (const float*)d_in[2];   // [16384,2]
    float* out = (float*)d_out;

    float* w2 = (float*)((char*)d_ws + WS_W2_OFF);
    unsigned long long* packed = (unsigned long long*)((char*)d_ws + WS_PACKED_OFF);

    hipMemsetAsync(packed, 0xFF, B_DIM * sizeof(unsigned long long), stream);
    w2_kernel<<<N_DIM / 4, 256, 0, stream>>>(W, w2);

    if (ws_size >= (size_t)WS_FAST_NEED) {
        unsigned short* Xh = (unsigned short*)((char*)d_ws + WS_PLANES_OFF);
        unsigned short* Xl = (unsigned short*)((char*)Xh + XPLANE_BYTES);
        unsigned short* Wh = (unsigned short*)((char*)Xl + XPLANE_BYTES);
        unsigned short* Wl = (unsigned short*)((char*)Wh + WPLANE_BYTES);
        convert_planes<<<(B_DIM + N_DIM) * 32 / 256, 256, 0, stream>>>(X, W, Xh, Xl, Wh, Wl);
        som_fast<<<(B_DIM / BM) * (N_DIM / BN), 256, 0, stream>>>(Xh, Xl, Wh, Wl, w2, packed);
    } else {
        som_mfma<<<(B_DIM / BM) * (N_DIM / BN), 256, 0, stream>>>(X, W, w2, packed);
    }
    finalize<<<B_DIM / 4, 256, 0, stream>>>(X, L, packed, out);
}